// Round 10
// baseline (2797.169 us; speedup 1.0000x reference)
//
#include <hip/hip_runtime.h>
#include <hip/hip_bf16.h>
#include <math.h>

// Problem constants
constexpr int NB  = 32;      // batch
constexpr int NS  = 256;     // seq len
constexpr int NE  = 1024;    // embed dim
constexpr int NH  = 1024;    // LSTM output dim (2*NHD)
constexpr int NHD = 512;     // per-direction hidden
constexpr int NG  = 2048;    // 4*NHD gates
constexpr int NP  = 16;      // prompt positions
constexpr int NBS = NB * NS; // 8192 rows
constexpr int GK  = 1024;    // GEMM K (= NE = NH)

// Persistent LSTM decomposition: UPW=16 units/WG, 32 WGs/dir, 64 total
constexpr int UPW  = 16;
constexpr int NWGD = NHD / UPW;  // 32 WGs per direction
// Gt layout: [d][slice 32][t 256][b 32][uloc 16][gate 4] fp32
constexpr size_t GT_DIR = (size_t)NWGD * 256 * 2048;   // 16.7M elems/dir

typedef __attribute__((ext_vector_type(8))) short bf16x8;
typedef __attribute__((ext_vector_type(4))) float f32x4;
typedef unsigned short u16;

__device__ __forceinline__ float sigm(float x) {
    return __fdividef(1.0f, 1.0f + __expf(-x));
}
__device__ __forceinline__ float tanhfast(float x) {
    float t = __expf(2.0f * x);
    return 1.0f - __fdividef(2.0f, t + 1.0f);
}
__device__ __forceinline__ u16 f2bf(float f) {
    union { float f; unsigned u; } v; v.f = f;
    unsigned r = v.u + 0x7FFF + ((v.u >> 16) & 1);   // RNE
    return (u16)(r >> 16);
}
__device__ __forceinline__ float bf2f(u16 b) {
    return __uint_as_float((unsigned)b << 16);
}

// ---------------------------------------------------------------------------
__global__ void k_zero(int* p) { p[blockIdx.x * 256 + threadIdx.x] = 0; }

// ---------------------------------------------------------------------------
// allb_bf[s][b][1024] (bf16) = emb[id]+ctx[id], prompt_emb at prompt slots
// ---------------------------------------------------------------------------
__global__ void k_allb(const float* __restrict__ emb, const float* __restrict__ ctx,
                       const float* __restrict__ pemb, const int* __restrict__ ids,
                       const int* __restrict__ pidx, u16* __restrict__ allb) {
    int r = blockIdx.x;            // r = b*NS + s
    int b = r >> 8, s = r & 255;
    __shared__ int ppos;
    if (threadIdx.x == 0) {
        int t = -1;
        #pragma unroll
        for (int p = 0; p < NP; ++p)
            if (pidx[b * NP + p] == s) t = p;
        ppos = t;
    }
    __syncthreads();
    int e = threadIdx.x;
    float4 v;
    if (ppos >= 0) {
        v = ((const float4*)(pemb + (size_t)ppos * NE))[e];
    } else {
        int id = ids[r];
        float4 a = ((const float4*)(emb + (size_t)id * NE))[e];
        float4 c = ((const float4*)(ctx + (size_t)id * NE))[e];
        v = make_float4(a.x + c.x, a.y + c.y, a.z + c.z, a.w + c.w);
    }
    ushort4 o;
    o.x = f2bf(v.x); o.y = f2bf(v.y); o.z = f2bf(v.z); o.w = f2bf(v.w);
    *(ushort4*)(allb + ((size_t)(s * NB + b)) * NE + e * 4) = o;
}

// ---------------------------------------------------------------------------
__global__ void k_raw(const float* __restrict__ emb, const int* __restrict__ ids,
                      float* __restrict__ out) {
    int r = blockIdx.x;
    int id = ids[r];
    ((float4*)(out + (size_t)r * NE))[threadIdx.x] =
        ((const float4*)(emb + (size_t)id * NE))[threadIdx.x];
}

// ---------------------------------------------------------------------------
// Wih ([2][2048][1024] fp32, gate-major rows) -> Wbf (bf16, UNIT-MAJOR rows:
// n' = unit*4+gate) + combined bias in same order.
// ---------------------------------------------------------------------------
__global__ void k_wcvt(const float* __restrict__ Wih, const float* __restrict__ bih,
                       const float* __restrict__ bhh, u16* __restrict__ Wbf,
                       float* __restrict__ biasC) {
    int blk = blockIdx.x;               // [2][2048]
    int d = blk >> 11, np = blk & 2047;
    int rw = (np & 3) * 512 + (np >> 2);
    const float* src = Wih + ((size_t)d * NG + rw) * GK;
    u16* dst = Wbf + ((size_t)d * NG + np) * GK;
    int t = threadIdx.x;
    float4 v = ((const float4*)src)[t];
    ushort4 o;
    o.x = f2bf(v.x); o.y = f2bf(v.y); o.z = f2bf(v.z); o.w = f2bf(v.w);
    ((ushort4*)dst)[t] = o;
    if (t == 0)
        biasC[d * NG + np] = bih[d * NG + rw] + bhh[d * NG + rw];
}

// ---------------------------------------------------------------------------
// bf16 MFMA GEMM: Gt = A[m',k] @ Wbf[n',k]^T + biasC  (proven R5 structure)
// ---------------------------------------------------------------------------
__global__ __launch_bounds__(256) void k_gemm_m(const u16* __restrict__ A0,
                                                const u16* __restrict__ A1,
                                                int astride,
                                                const u16* __restrict__ W,
                                                const float* __restrict__ bc,
                                                float* __restrict__ Gt) {
    __shared__ char At[128 * 128];
    __shared__ char Wt[128 * 128];
    int tid = threadIdx.x;
    int lane = tid & 63, w = tid >> 6;
    int n0 = blockIdx.x * 128, m0 = blockIdx.y * 128;
    int r = tid >> 1, h = tid & 1;      // staging: row r, half h

    f32x4 acc[4][4];
    #pragma unroll
    for (int i = 0; i < 4; ++i)
        #pragma unroll
        for (int j = 0; j < 4; ++j) acc[i][j] = (f32x4){0.f, 0.f, 0.f, 0.f};

    unsigned rsw = (unsigned)((r & 7) << 4);
    for (int kt = 0; kt < GK; kt += 64) {
        {
            int k0 = kt + h * 32;
            const u16* asrc = (k0 < 512) ? (A0 + (size_t)(m0 + r) * astride + k0)
                                         : (A1 + (size_t)(m0 + r) * astride + (k0 - 512));
            const u16* wsrc = W + (size_t)(n0 + r) * GK + k0;
            #pragma unroll
            for (int j = 0; j < 4; ++j) {
                uint4 va = *(const uint4*)(asrc + j * 8);
                *(uint4*)(At + r * 128 + (((unsigned)(h * 64 + j * 16)) ^ rsw)) = va;
                uint4 vw = *(const uint4*)(wsrc + j * 8);
                *(uint4*)(Wt + r * 128 + (((unsigned)(h * 64 + j * 16)) ^ rsw)) = vw;
            }
        }
        __syncthreads();
        #pragma unroll
        for (int sub = 0; sub < 2; ++sub) {
            bf16x8 af[4], bfr[4];
            int kbyte = sub * 64 + (lane >> 4) * 16;
            #pragma unroll
            for (int ni = 0; ni < 4; ++ni) {
                int rr = (w & 1) * 64 + ni * 16 + (lane & 15);
                af[ni] = *(const bf16x8*)(Wt + rr * 128 + ((unsigned)kbyte ^ ((unsigned)((rr & 7) << 4))));
            }
            #pragma unroll
            for (int mi = 0; mi < 4; ++mi) {
                int rr = (w >> 1) * 64 + mi * 16 + (lane & 15);
                bfr[mi] = *(const bf16x8*)(At + rr * 128 + ((unsigned)kbyte ^ ((unsigned)((rr & 7) << 4))));
            }
            #pragma unroll
            for (int mi = 0; mi < 4; ++mi)
                #pragma unroll
                for (int ni = 0; ni < 4; ++ni)
                    acc[mi][ni] = __builtin_amdgcn_mfma_f32_16x16x32_bf16(
                        af[ni], bfr[mi], acc[mi][ni], 0, 0, 0);
        }
        __syncthreads();
    }
    // epilogue: float4 (4 gates of one unit) -> Gt[slice][t][b][uloc][g]
    #pragma unroll
    for (int mi = 0; mi < 4; ++mi) {
        int mp = m0 + (w >> 1) * 64 + mi * 16 + (lane & 15);
        int t = mp >> 5, b = mp & 31;
        #pragma unroll
        for (int ni = 0; ni < 4; ++ni) {
            int npb = n0 + (w & 1) * 64 + ni * 16 + (lane >> 4) * 4;
            int unit = npb >> 2;
            float4 bv = *(const float4*)(bc + npb);
            f32x4 a = acc[mi][ni];
            float4 o = make_float4(a[0] + bv.x, a[1] + bv.y, a[2] + bv.z, a[3] + bv.w);
            *(float4*)(Gt + ((size_t)((unit >> 4) * NS + t)) * 2048 + b * 64 + (unit & 15) * 4) = o;
        }
    }
}

// ---------------------------------------------------------------------------
// Pipelined dual-chain persistent MFMA LSTM.
// Batch rows 0-15 (chain A) and 16-31 (chain B) are independent recurrences.
// Per step, 4 phases so every LLC round-trip hides under other-chain work:
//  P1: compute A(t) from LDS-A; write stageB(t-1) regs -> LDS-B (loads were
//      issued last iter, drain under A's MFMAs); store hA; vmcnt; sync;
//      publish A(t) to own 64B line.
//  P2: compute B(t) from LDS-B; store hB; vmcnt; sync; publish B(t).
//  P3: poll A(t) lines (propagated during P2 -> first-try hit); prefetch
//      G(t+1); issue stage-A loads.
//  P4: poll B(t) (implicit vmcnt drains stage-A; B propagated meanwhile);
//      write stage-A -> LDS-A; issue stage-B loads (stay in flight into
//      next P1); sync.
// Same proven primitives as R9 (relaxed agent store/publish, monotonic
// step-indexed lines, per-launch zeroing); uniform control flow, publishes
// precede any poll each step -> inductive progress, no deadlock.
// ---------------------------------------------------------------------------
__global__ __launch_bounds__(256) void k_lstm_q(const float* __restrict__ Gt,
                                                const float* __restrict__ Whh,
                                                u16* __restrict__ hxb,
                                                int* __restrict__ cblk) {
    __shared__ char hldsA[16 * 1024];      // 16 KB, chain A (batches 0-15)
    __shared__ char hldsB[16 * 1024];      // 16 KB, chain B (batches 16-31)
    int wg = blockIdx.x;
    int d = wg & 1;
    int slice = wg >> 1;            // 0..31
    int n0 = slice * UPW;
    int tid = threadIdx.x;
    int lane = tid & 63;
    int w = tid >> 6;               // wave 0..3
    int* linesA  = cblk + d * 1024;        // 32 lines x 16 ints
    int* linesB  = linesA + 512;
    int* mylineA = linesA + slice * 16;
    int* mylineB = linesB + slice * 16;
    int pollidx  = (lane & 31) * 16;       // lane polls one line (2x cover)
    u16* hxd = hxb + (size_t)d * NS * NB * NHD;
    const float* Gd = Gt + (size_t)d * GT_DIR + (size_t)slice * NS * 2048;

    // resident A fragments (Whh fp32 -> bf16); per-wave-unique rows
    bf16x8 wfrag[16];
    {
        int rloc = lane & 15;
        int usub = rloc >> 2, g = rloc & 3;
        int kb0 = lane >> 4;
        const float* wrow = Whh + ((size_t)d * NG + g * NHD + n0 + 4 * w + usub) * NHD;
        #pragma unroll
        for (int kk = 0; kk < 16; ++kk) {
            const float* p = wrow + kk * 32 + kb0 * 8;
            float4 x = *(const float4*)p;
            float4 y = *(const float4*)(p + 4);
            bf16x8 wf;
            wf[0] = (short)f2bf(x.x); wf[1] = (short)f2bf(x.y);
            wf[2] = (short)f2bf(x.z); wf[3] = (short)f2bf(x.w);
            wf[4] = (short)f2bf(y.x); wf[5] = (short)f2bf(y.y);
            wf[6] = (short)f2bf(y.z); wf[7] = (short)f2bf(y.w);
            wfrag[kk] = wf;
        }
    }
    int uloc  = 4 * w + (lane >> 4);       // C-layout unit within slice
    int unitC = n0 + uloc;                 // global unit
    int bA    = lane & 15;                 // chain-A batch (0-15)
    int bB    = 16 + bA;                   // chain-B batch (16-31)
    int kb    = lane >> 4;                 // B-fragment k-block
    unsigned rdsw = (unsigned)((bA & 7) << 4);   // read swizzle (A and B same)
    int sRow = tid >> 4;                   // staging row 0..15
    int sC   = tid & 15;                   // 64B chunk within row
    unsigned srsw = (unsigned)((sRow & 7) << 4);

    float cA = 0.f, cB = 0.f;
    uint4 stA[4], stB[4];                  // staged h regs (16B x4 = 64B)
    // prologue: G prefetch for step 0
    int tt0 = d ? (NS - 1) : 0;
    float4 GvA = *(const float4*)(Gd + (size_t)tt0 * 2048 + bA * 64 + uloc * 4);
    float4 GvB = *(const float4*)(Gd + (size_t)tt0 * 2048 + bB * 64 + uloc * 4);

    for (int step = 0; step < NS; ++step) {
        int tt = d ? (NS - 1 - step) : step;
        // ================= P1: chain A compute =================
        f32x4 accA = {0.f, 0.f, 0.f, 0.f};
        if (step) {
            const char* abase = hldsA + bA * 1024;
            #pragma unroll
            for (int kk = 0; kk < 16; ++kk) {
                bf16x8 bfv = *(const bf16x8*)(abase + (((unsigned)(kk * 64 + kb * 16)) ^ rdsw));
                accA = __builtin_amdgcn_mfma_f32_16x16x32_bf16(wfrag[kk], bfv, accA, 0, 0, 0);
            }
        }
        {
            float ig = sigm(accA[0] + GvA.x);
            float fg = sigm(accA[1] + GvA.y);
            float gg = tanhfast(accA[2] + GvA.z);
            float og = sigm(accA[3] + GvA.w);
            cA = fg * cA + ig * gg;
            float hv = og * tanhfast(cA);
            __hip_atomic_store(hxd + ((size_t)tt * NB + bA) * NHD + unitC, f2bf(hv),
                               __ATOMIC_RELAXED, __HIP_MEMORY_SCOPE_AGENT);
        }
        if (step) {
            // write stageB(t-1) -> LDS-B (loads issued last iter, now drained
            // under A's MFMAs; compiler inserts the needed vmcnt)
            char* dr = hldsB + sRow * 1024;
            #pragma unroll
            for (int i = 0; i < 4; ++i)
                *(uint4*)(dr + (((unsigned)(sC * 64 + i * 16)) ^ srsw)) = stB[i];
        }
        asm volatile("s_waitcnt vmcnt(0)" ::: "memory");
        __syncthreads();
        if (tid == 0)
            __hip_atomic_store(mylineA, step + 1, __ATOMIC_RELAXED,
                               __HIP_MEMORY_SCOPE_AGENT);
        // ================= P2: chain B compute =================
        f32x4 accB = {0.f, 0.f, 0.f, 0.f};
        if (step) {
            const char* bbase = hldsB + bA * 1024;   // row index = bA (0-15)
            #pragma unroll
            for (int kk = 0; kk < 16; ++kk) {
                bf16x8 bfv = *(const bf16x8*)(bbase + (((unsigned)(kk * 64 + kb * 16)) ^ rdsw));
                accB = __builtin_amdgcn_mfma_f32_16x16x32_bf16(wfrag[kk], bfv, accB, 0, 0, 0);
            }
        }
        {
            float ig = sigm(accB[0] + GvB.x);
            float fg = sigm(accB[1] + GvB.y);
            float gg = tanhfast(accB[2] + GvB.z);
            float og = sigm(accB[3] + GvB.w);
            cB = fg * cB + ig * gg;
            float hv = og * tanhfast(cB);
            __hip_atomic_store(hxd + ((size_t)tt * NB + bB) * NHD + unitC, f2bf(hv),
                               __ATOMIC_RELAXED, __HIP_MEMORY_SCOPE_AGENT);
        }
        asm volatile("s_waitcnt vmcnt(0)" ::: "memory");
        __syncthreads();
        if (tid == 0)
            __hip_atomic_store(mylineB, step + 1, __ATOMIC_RELAXED,
                               __HIP_MEMORY_SCOPE_AGENT);
        if (step == NS - 1) break;       // last step: no exchange needed
        int target = step + 1;
        // ================= P3: poll A, prefetch, issue stage-A =============
        for (;;) {
            int v = __hip_atomic_load(linesA + pollidx, __ATOMIC_RELAXED,
                                      __HIP_MEMORY_SCOPE_AGENT);
            if (__all(v >= target)) break;
            __builtin_amdgcn_s_sleep(1);
        }
        {
            int ttn = d ? tt - 1 : tt + 1;
            GvA = *(const float4*)(Gd + (size_t)ttn * 2048 + bA * 64 + uloc * 4);
            GvB = *(const float4*)(Gd + (size_t)ttn * 2048 + bB * 64 + uloc * 4);
        }
        {
            const u16* sa = hxd + ((size_t)tt * NB + sRow) * NHD + sC * 32;
            #pragma unroll
            for (int i = 0; i < 4; ++i) stA[i] = *(const uint4*)(sa + i * 8);
        }
        asm volatile("" ::: "memory");   // pin stage-A issue before poll B
        // ================= P4: poll B, write LDS-A, issue stage-B ==========
        for (;;) {
            int v = __hip_atomic_load(linesB + pollidx, __ATOMIC_RELAXED,
                                      __HIP_MEMORY_SCOPE_AGENT);
            if (__all(v >= target)) break;
            __builtin_amdgcn_s_sleep(1);
        }
        {
            char* da = hldsA + sRow * 1024;
            #pragma unroll
            for (int i = 0; i < 4; ++i)
                *(uint4*)(da + (((unsigned)(sC * 64 + i * 16)) ^ srsw)) = stA[i];
        }
        {
            const u16* sb = hxd + ((size_t)tt * NB + 16 + sRow) * NHD + sC * 32;
            #pragma unroll
            for (int i = 0; i < 4; ++i) stB[i] = *(const uint4*)(sb + i * 8);
        }
        __syncthreads();                 // LDS-A visible for next P1
    }
}

// ---------------------------------------------------------------------------
// MLP stage 1: mid[512][1024] = relu(hrow @ W1^T + b1), rows from hx_bf
// ---------------------------------------------------------------------------
__global__ __launch_bounds__(256) void k_mlp1(const u16* __restrict__ hxb,
                                              const int* __restrict__ pidx,
                                              const float* __restrict__ W1,
                                              const float* __restrict__ b1,
                                              float* __restrict__ mid) {
    __shared__ float As[16][65];
    __shared__ float Ws[16][65];
    int tid = threadIdx.x;
    int tx = tid & 15, ty = tid >> 4;
    int n0 = blockIdx.x * 64, m0 = blockIdx.y * 64;
    int lr = tid >> 2;
    int lk = (tid & 3) * 4;
    int m = m0 + lr;
    int bb = m >> 4;
    int s = pidx[m];
    float acc[4][4] = {};
    for (int kt = 0; kt < GK; kt += 16) {
        int k0 = kt + lk;
        int half = k0 >> 9;
        ushort4 av4 = *(const ushort4*)(hxb + (((size_t)(half * NS + s)) * NB + bb) * NHD + (k0 & 511));
        float4 wv = *(const float4*)(W1 + (size_t)(n0 + lr) * GK + k0);
        As[lk + 0][lr] = bf2f(av4.x); As[lk + 1][lr] = bf2f(av4.y);
        As[lk + 2][lr] = bf2f(av4.z); As[lk + 3][lr] = bf2f(av4.w);
        Ws[lk + 0][lr] = wv.x; Ws[lk + 1][lr] = wv.y;
        Ws[lk + 2][lr] = wv.z; Ws[lk + 3][lr] = wv.w;
        __syncthreads();
        #pragma unroll
        for (int kk = 0; kk < 16; ++kk) {
            float a[4], wv2[4];
            #pragma unroll
            for (int i = 0; i < 4; ++i) a[i] = As[kk][ty * 4 + i];
            #pragma unroll
            for (int j = 0; j < 4; ++j) wv2[j] = Ws[kk][tx * 4 + j];
            #pragma unroll
            for (int i = 0; i < 4; ++i)
                #pragma unroll
                for (int j = 0; j < 4; ++j) acc[i][j] += a[i] * wv2[j];
        }
        __syncthreads();
    }
    #pragma unroll
    for (int j = 0; j < 4; ++j) {
        int n = n0 + tx * 4 + j;
        float bias = b1[n];
        #pragma unroll
        for (int i = 0; i < 4; ++i)
            mid[(size_t)(m0 + ty * 4 + i) * 1024 + n] = fmaxf(acc[i][j] + bias, 0.f);
    }
}

// ---------------------------------------------------------------------------
// MLP stage 2: out[b, s] = mid @ W2^T + b2 + pemb[p], scattered to d_out.
// ---------------------------------------------------------------------------
__global__ __launch_bounds__(256) void k_mlp2(const float* __restrict__ mid,
                                              const int* __restrict__ pidx,
                                              const float* __restrict__ W2,
                                              const float* __restrict__ b2,
                                              const float* __restrict__ pemb,
                                              float* __restrict__ out) {
    __shared__ float As[16][65];
    __shared__ float Ws[16][65];
    int tid = threadIdx.x;
    int tx = tid & 15, ty = tid >> 4;
    int n0 = blockIdx.x * 64, m0 = blockIdx.y * 64;
    int lr = tid >> 2;
    int lk = (tid & 3) * 4;
    float acc[4][4] = {};
    for (int kt = 0; kt < GK; kt += 16) {
        float4 av = *(const float4*)(mid + (size_t)(m0 + lr) * GK + kt + lk);
        float4 wv = *(const float4*)(W2 + (size_t)(n0 + lr) * GK + kt + lk);
        As[lk + 0][lr] = av.x; As[lk + 1][lr] = av.y;
        As[lk + 2][lr] = av.z; As[lk + 3][lr] = av.w;
        Ws[lk + 0][lr] = wv.x; Ws[lk + 1][lr] = wv.y;
        Ws[lk + 2][lr] = wv.z; Ws[lk + 3][lr] = wv.w;
        __syncthreads();
        #pragma unroll
        for (int kk = 0; kk < 16; ++kk) {
            float a[4], wv2[4];
            #pragma unroll
            for (int i = 0; i < 4; ++i) a[i] = As[kk][ty * 4 + i];
            #pragma unroll
            for (int j = 0; j < 4; ++j) wv2[j] = Ws[kk][tx * 4 + j];
            #pragma unroll
            for (int i = 0; i < 4; ++i)
                #pragma unroll
                for (int j = 0; j < 4; ++j) acc[i][j] += a[i] * wv2[j];
        }
        __syncthreads();
    }
    #pragma unroll
    for (int i = 0; i < 4; ++i) {
        int m = m0 + ty * 4 + i;
        int bb = m >> 4, p = m & 15;
        int s = pidx[m];
        float* orow = out + ((size_t)(bb * NS + s)) * NE;
        const float* prow = pemb + (size_t)p * NE;
        #pragma unroll
        for (int j = 0; j < 4; ++j) {
            int n = n0 + tx * 4 + j;
            orow[n] = acc[i][j] + b2[n] + prow[n];
        }
    }
}

// ---------------------------------------------------------------------------
extern "C" void kernel_launch(void* const* d_in, const int* in_sizes, int n_in,
                              void* d_out, int out_size, void* d_ws, size_t ws_size,
                              hipStream_t stream) {
    const float* emb  = (const float*)d_in[0];
    const float* ctx  = (const float*)d_in[1];
    const float* pemb = (const float*)d_in[2];
    const float* Wih0 = (const float*)d_in[3];
    const float* Whh0 = (const float*)d_in[4];
    const float* bih0 = (const float*)d_in[5];
    const float* bhh0 = (const float*)d_in[6];
    const float* Wih1 = (const float*)d_in[7];
    const float* Whh1 = (const float*)d_in[8];
    const float* bih1 = (const float*)d_in[9];
    const float* bhh1 = (const float*)d_in[10];
    const float* W1   = (const float*)d_in[11];
    const float* b1   = (const float*)d_in[12];
    const float* W2   = (const float*)d_in[13];
    const float* b2   = (const float*)d_in[14];
    const int* ids    = (const int*)d_in[15];
    const int* pidx   = (const int*)d_in[16];
    float* out = (float*)d_out;

    // Workspace layout (bytes):
    //   Gt:    [2][32][256][2048] f32 = 134217728
    //   allb:  [256][32][1024] bf16   =  16777216
    //   hx_bf: [2][256][32][512] bf16 =  16777216
    //   Wbf:   [2][2048][1024] bf16   =   8388608
    //   biasC: [2][2048] f32          =     16384
    //   mid:   [512][1024] f32        =   2097152
    //   ctr:   4096 ints (2 layers x 2 dirs x 2 chains x 32 lines x 16 ints)
    char* ws = (char*)d_ws;
    float* Gt    = (float*)ws;
    u16*   allb  = (u16*)(ws + 134217728u);
    u16*   hx    = (u16*)(ws + 150994944u);
    u16*   Wbf   = (u16*)(ws + 167772160u);
    float* biasC = (float*)(ws + 176160768u);
    float* mid   = (float*)(ws + 176177152u);
    int*   ctr   = (int*)(ws + 178274304u);

    k_zero<<<dim3(16), dim3(256), 0, stream>>>(ctr);
    k_allb<<<dim3(NBS), dim3(256), 0, stream>>>(emb, ctx, pemb, ids, pidx, allb);

    // Layer 0
    k_wcvt<<<dim3(2 * NG), dim3(256), 0, stream>>>(Wih0, bih0, bhh0, Wbf, biasC);
    for (int d = 0; d < 2; ++d)
        k_gemm_m<<<dim3(NG / 128, NBS / 128), dim3(256), 0, stream>>>(
            allb, allb + 512, 1024, Wbf + (size_t)d * NG * GK, biasC + d * NG,
            Gt + (size_t)d * GT_DIR);
    k_lstm_q<<<dim3(2 * NWGD), dim3(256), 0, stream>>>(Gt, Whh0, hx, ctr);

    k_raw<<<dim3(NBS), dim3(256), 0, stream>>>(emb, ids, out);

    // Layer 1 (A = hx_bf, dir halves)
    k_wcvt<<<dim3(2 * NG), dim3(256), 0, stream>>>(Wih1, bih1, bhh1, Wbf, biasC);
    for (int d = 0; d < 2; ++d)
        k_gemm_m<<<dim3(NG / 128, NBS / 128), dim3(256), 0, stream>>>(
            hx, hx + (size_t)NS * NB * NHD, 512, Wbf + (size_t)d * NG * GK,
            biasC + d * NG, Gt + (size_t)d * GT_DIR);
    k_lstm_q<<<dim3(2 * NWGD), dim3(256), 0, stream>>>(Gt, Whh1, hx, ctr + 2048);

    // MLP head at prompt rows
    k_mlp1<<<dim3(16, 8), dim3(256), 0, stream>>>(hx, pidx, W1, b1, mid);
    k_mlp2<<<dim3(16, 8), dim3(256), 0, stream>>>(mid, pidx, W2, b2, pemb, out);
}